// Round 1
// baseline (1490.798 us; speedup 1.0000x reference)
//
#include <hip/hip_runtime.h>

typedef _Float16 f16;
typedef __attribute__((ext_vector_type(8))) _Float16 f16x8;
typedef __attribute__((ext_vector_type(4))) float f32x4;

#define SC_CONV 0.014731391274719738f   /* 1/sqrt(512*9) */
#define SC_RGB  0.04419417382415922f    /* 1/sqrt(512)   */
#define SC_LIN  0.04419417382415922f    /* 1/sqrt(512)   */
#define SQRT2F  1.4142135623730951f

__device__ inline f16x8 zero_f16x8() {
    f16x8 v;
    #pragma unroll
    for (int i = 0; i < 8; ++i) v[i] = (_Float16)0.0f;
    return v;
}
__device__ inline f32x4 zero_f32x4() {
    f32x4 v;
    #pragma unroll
    for (int i = 0; i < 4; ++i) v[i] = 0.0f;
    return v;
}

// ---------------- styles: s_k[b,o] = style[b,:] @ (mod_w*sc).T + mod_b ----------------
__global__ __launch_bounds__(256) void k_styles(
    const float* __restrict__ style,
    const float* __restrict__ m1w, const float* __restrict__ m1b,
    const float* __restrict__ m2w, const float* __restrict__ m2b,
    const float* __restrict__ m3w, const float* __restrict__ m3b,
    float* __restrict__ s1, float* __restrict__ s2, float* __restrict__ s3)
{
    int g = blockIdx.x * 256 + threadIdx.x;      // 0..1535
    int set = g >> 9, o = g & 511;
    const float* mw = set == 0 ? m1w : set == 1 ? m2w : m3w;
    const float* mb = set == 0 ? m1b : set == 1 ? m2b : m3b;
    float* out = set == 0 ? s1 : set == 1 ? s2 : s3;
    float acc[8] = {0,0,0,0,0,0,0,0};
    for (int i = 0; i < 512; ++i) {
        float w = mw[o * 512 + i];
        #pragma unroll
        for (int b = 0; b < 8; ++b) acc[b] += style[b * 512 + i] * w;
    }
    #pragma unroll
    for (int b = 0; b < 8; ++b) out[b * 512 + o] = acc[b] * SC_LIN + mb[o];
}

// ---------------- demod: d[b,o] = rsqrt(sc^2 * sum_i s[b,i]^2 * sum_t w[o,i,t]^2 + eps) ----
__global__ __launch_bounds__(256) void k_demod(
    const float* __restrict__ w1, const float* __restrict__ s1, float* __restrict__ d1,
    const float* __restrict__ w2, const float* __restrict__ s2, float* __restrict__ d2)
{
    const int o = blockIdx.x, set = blockIdx.y;
    const float* w = set ? w2 : w1;
    const float* s = set ? s2 : s1;
    float* d = set ? d2 : d1;
    float acc[8] = {0,0,0,0,0,0,0,0};
    for (int i = threadIdx.x; i < 512; i += 256) {
        const float* wp = w + ((size_t)o * 512 + i) * 9;
        float sw = 0.f;
        #pragma unroll
        for (int t = 0; t < 9; ++t) { float vv = wp[t]; sw += vv * vv; }
        #pragma unroll
        for (int b = 0; b < 8; ++b) { float sv = s[b * 512 + i]; acc[b] += sv * sv * sw; }
    }
    __shared__ float red[8][4];
    const int lane = threadIdx.x & 63, wid = threadIdx.x >> 6;
    #pragma unroll
    for (int b = 0; b < 8; ++b)
        #pragma unroll
        for (int off = 1; off < 64; off <<= 1)
            acc[b] += __shfl_xor(acc[b], off);
    if (lane == 0) {
        #pragma unroll
        for (int b = 0; b < 8; ++b) red[b][wid] = acc[b];
    }
    __syncthreads();
    if (threadIdx.x < 8) {
        float t = red[threadIdx.x][0] + red[threadIdx.x][1] + red[threadIdx.x][2] + red[threadIdx.x][3];
        d[threadIdx.x * 512 + o] = rsqrtf(t * (SC_CONV * SC_CONV) + 1e-8f);
    }
}

// ---------------- weight prep: wA[tap][o][i] = f16(w[o][i][tap]) ----------------
__global__ __launch_bounds__(256) void k_prep_w(
    const float* __restrict__ w1, const float* __restrict__ w2,
    f16* __restrict__ wA1, f16* __restrict__ wA2)
{
    int g = blockIdx.x * 256 + threadIdx.x;     // over 2*512*512
    int set = g >> 18; int oi = g & 262143;
    int o = oi >> 9, i = oi & 511;
    const float* w = (set ? w2 : w1) + (size_t)oi * 9;
    f16* wa = set ? wA2 : wA1;
    #pragma unroll
    for (int t = 0; t < 9; ++t)
        wa[((size_t)t * 512 + o) * 512 + i] = (f16)w[t];
}

// ---------------- x prep: xm[b][u][v][i] = f16(x[b,i,u,v] * s1[b,i] * sc) (NHWC) --------
__global__ __launch_bounds__(256) void k_prep_x(
    const float* __restrict__ x, const float* __restrict__ s1, f16* __restrict__ xm)
{
    int u = blockIdx.x, b = blockIdx.y;
    __shared__ float t[32][33];
    int tx = threadIdx.x & 31, ty = threadIdx.x >> 5;   // 32 x 8
    for (int ic = 0; ic < 512; ic += 32) {
        #pragma unroll
        for (int k = 0; k < 4; ++k) {
            int i = ic + ty + 8 * k;
            t[ty + 8 * k][tx] = x[(((size_t)b * 512 + i) * 32 + u) * 32 + tx];
        }
        __syncthreads();
        #pragma unroll
        for (int k = 0; k < 4; ++k) {
            int v = ty + 8 * k;
            int i = ic + tx;
            float sv = s1[b * 512 + i] * SC_CONV;
            xm[(((size_t)b * 32 + u) * 32 + v) * 512 + i] = (f16)(t[tx][v] * sv);
        }
        __syncthreads();
    }
}

// ---------------- conv1: 4-phase conv-transpose (stride2, 3x3) via MFMA -----------------
// ct[m][n], m=2u'+p, n=2v'+q ; taps: ty = p+2ay (u = u'-ay), tx = q+2ax (v = v'-ax)
// writes ctp[b][o][1+m][1+n] (f16, 68x68 halo buffer, borders pre-zeroed)
__global__ __launch_bounds__(256) void k_conv1(
    const f16* __restrict__ xm, const f16* __restrict__ wA1, f16* __restrict__ ctp)
{
    const int b = blockIdx.z >> 1, q = blockIdx.z & 1;
    const int m = blockIdx.y, p = m & 1, up = m >> 1;
    const int lane = threadIdx.x & 63, wid = threadIdx.x >> 6;
    const int oW = blockIdx.x * 128 + wid * 32;
    const int lr = lane & 15, lk = lane >> 4;
    f32x4 acc[2][3];
    #pragma unroll
    for (int a = 0; a < 2; ++a)
        #pragma unroll
        for (int c = 0; c < 3; ++c) acc[a][c] = zero_f32x4();
    const int nty = p ? 1 : 2, ntx = q ? 1 : 2;
    for (int ay = 0; ay < nty; ++ay) {
        int u = up - ay;
        if (u < 0 || u >= 32) continue;
        int ty = p + 2 * ay;
        const f16* xr = xm + ((size_t)b * 32 + u) * 32 * 512;
        for (int ax = 0; ax < ntx; ++ax) {
            int txp = q + 2 * ax;
            const f16* wt = wA1 + (size_t)(ty * 3 + txp) * 512 * 512;
            for (int ic = 0; ic < 512; ic += 32) {
                f16x8 af[2], bf[3];
                #pragma unroll
                for (int mt = 0; mt < 2; ++mt)
                    af[mt] = *(const f16x8*)(wt + (size_t)(oW + mt * 16 + lr) * 512 + ic + lk * 8);
                #pragma unroll
                for (int nt = 0; nt < 3; ++nt) {
                    int v = nt * 16 + lr - ax;
                    bf[nt] = (v >= 0 && v < 32)
                        ? *(const f16x8*)(xr + (size_t)v * 512 + ic + lk * 8)
                        : zero_f16x8();
                }
                #pragma unroll
                for (int mt = 0; mt < 2; ++mt)
                    #pragma unroll
                    for (int nt = 0; nt < 3; ++nt)
                        acc[mt][nt] = __builtin_amdgcn_mfma_f32_16x16x32_f16(
                            af[mt], bf[nt], acc[mt][nt], 0, 0, 0);
            }
        }
    }
    const int row = 1 + m;
    #pragma unroll
    for (int mt = 0; mt < 2; ++mt)
        #pragma unroll
        for (int nt = 0; nt < 3; ++nt) {
            int vp = nt * 16 + lr;
            if (vp >= 33 - q) continue;
            int col = 1 + 2 * vp + q;
            #pragma unroll
            for (int r = 0; r < 4; ++r) {
                int o = oW + mt * 16 + lk * 4 + r;
                ctp[(((size_t)b * 512 + o) * 68 + row) * 68 + col] = (f16)acc[mt][nt][r];
            }
        }
}

// ---------------- blur1 + demod + noise + bias + lrelu + next-layer modulation ----------
// out1[y][x] = sum_{s,t<4} k1[s]k1[t]/16 * ctp[y+s][x+t]; then *d1 +nz +b1, lrelu*sqrt2, *s2*sc
// stored NHWC f16 in in1 via LDS transpose (coalesced 128B stores)
__global__ __launch_bounds__(256) void k_blur1(
    const f16* __restrict__ ctp, const float* __restrict__ d1,
    const float* __restrict__ noise1, const float* __restrict__ nw1,
    const float* __restrict__ bias1, const float* __restrict__ s2,
    f16* __restrict__ in1)
{
    const int oB = blockIdx.x * 64, y = blockIdx.y, b = blockIdx.z;
    const int tx = threadIdx.x, ty = threadIdx.y;   // 64 x 4
    __shared__ f16 T[64][66];
    const float kk[4] = {1.f, 3.f, 3.f, 1.f};
    float nz = nw1[0] * noise1[((size_t)b * 64 + y) * 64 + tx];
    for (int oi = 0; oi < 16; ++oi) {
        int ol = oi * 4 + ty, o = oB + ol;
        const f16* base = ctp + (((size_t)b * 512 + o) * 68 + y) * 68 + tx;
        float s = 0.f;
        #pragma unroll
        for (int sr = 0; sr < 4; ++sr)
            #pragma unroll
            for (int tc = 0; tc < 4; ++tc)
                s += kk[sr] * kk[tc] * (float)base[sr * 68 + tc];
        s *= (1.0f / 16.0f);
        float v = s * d1[b * 512 + o] + nz + bias1[o];
        v = (v > 0.f ? v : 0.2f * v) * SQRT2F;
        v *= s2[b * 512 + o] * SC_CONV;
        T[ol][tx] = (f16)v;
    }
    __syncthreads();
    #pragma unroll
    for (int xi = 0; xi < 16; ++xi) {
        int xx = xi * 4 + ty;
        in1[(((size_t)b * 64 + y) * 64 + xx) * 512 + oB + tx] = T[tx][xx];
    }
}

// ---------------- conv2: 3x3 pad1 implicit-GEMM MFMA + epilogue ----------------
__global__ __launch_bounds__(256) void k_conv2(
    const f16* __restrict__ in1, const f16* __restrict__ wA2,
    const float* __restrict__ d2, const float* __restrict__ noise2,
    const float* __restrict__ nw2, const float* __restrict__ bias2,
    const float* __restrict__ s3, f16* __restrict__ in2)
{
    const int b = blockIdx.z, y = blockIdx.y, oB = blockIdx.x * 64;
    const int lane = threadIdx.x & 63, wid = threadIdx.x >> 6;
    const int wm = wid >> 1, wn = wid & 1;
    const int lr = lane & 15, lk = lane >> 4;
    f32x4 acc[2][2];
    #pragma unroll
    for (int a = 0; a < 2; ++a)
        #pragma unroll
        for (int c = 0; c < 2; ++c) acc[a][c] = zero_f32x4();
    const f16* inb = in1 + (size_t)b * 64 * 64 * 512;
    for (int tap = 0; tap < 9; ++tap) {
        int dy = tap / 3 - 1, dx = tap % 3 - 1;
        int ry = y + dy;
        if (ry < 0 || ry >= 64) continue;
        const f16* wt = wA2 + (size_t)tap * 512 * 512;
        const f16* inr = inb + (size_t)ry * 64 * 512;
        for (int ic = 0; ic < 512; ic += 32) {
            f16x8 af[2], bf[2];
            #pragma unroll
            for (int mt = 0; mt < 2; ++mt)
                af[mt] = *(const f16x8*)(wt + (size_t)(oB + wm * 32 + mt * 16 + lr) * 512 + ic + lk * 8);
            #pragma unroll
            for (int nt = 0; nt < 2; ++nt) {
                int xx = wn * 32 + nt * 16 + lr + dx;
                bf[nt] = (xx >= 0 && xx < 64)
                    ? *(const f16x8*)(inr + (size_t)xx * 512 + ic + lk * 8)
                    : zero_f16x8();
            }
            #pragma unroll
            for (int mt = 0; mt < 2; ++mt)
                #pragma unroll
                for (int nt = 0; nt < 2; ++nt)
                    acc[mt][nt] = __builtin_amdgcn_mfma_f32_16x16x32_f16(
                        af[mt], bf[nt], acc[mt][nt], 0, 0, 0);
        }
    }
    __shared__ f16 T[64][66];
    float nw = nw2[0];
    #pragma unroll
    for (int mt = 0; mt < 2; ++mt)
        #pragma unroll
        for (int nt = 0; nt < 2; ++nt) {
            int xx = wn * 32 + nt * 16 + lr;
            float nz = nw * noise2[((size_t)b * 64 + y) * 64 + xx];
            #pragma unroll
            for (int r = 0; r < 4; ++r) {
                int ol = wm * 32 + mt * 16 + lk * 4 + r;
                int o = oB + ol;
                float v = acc[mt][nt][r] * d2[b * 512 + o] + nz + bias2[o];
                v = (v > 0.f ? v : 0.2f * v) * SQRT2F;
                v *= s3[b * 512 + o] * SC_RGB;
                T[ol][xx] = (f16)v;
            }
        }
    __syncthreads();
    const int o_l = threadIdx.x & 63, xg = threadIdx.x >> 6;
    #pragma unroll
    for (int k = 0; k < 16; ++k) {
        int xx = xg * 16 + k;
        in2[(((size_t)b * 64 + y) * 64 + xx) * 512 + oB + o_l] = T[o_l][xx];
    }
}

// ---------------- ToRGB: wave-per-pixel dot over 512 ch + bias + skip upfirdn -----------
__global__ __launch_bounds__(256) void k_rgb(
    const f16* __restrict__ in2, const float* __restrict__ w3,
    const float* __restrict__ bias3, const float* __restrict__ skiprgb,
    float* __restrict__ out)
{
    const int wid = threadIdx.x >> 6, lane = threadIdx.x & 63;
    const int pix = blockIdx.x * 4 + wid;            // 0..32767
    const int b = pix >> 12, rem = pix & 4095, y = rem >> 6, xx = rem & 63;
    const f16* ip = in2 + (size_t)pix * 512 + lane * 8;
    f16x8 v = *(const f16x8*)ip;
    float a[3] = {0.f, 0.f, 0.f};
    const float* wp = w3 + lane * 8;
    #pragma unroll
    for (int e = 0; e < 8; ++e) {
        float xv = (float)v[e];
        a[0] += xv * wp[e];
        a[1] += xv * wp[512 + e];
        a[2] += xv * wp[1024 + e];
    }
    #pragma unroll
    for (int c = 0; c < 3; ++c)
        #pragma unroll
        for (int off = 1; off < 64; off <<= 1)
            a[c] += __shfl_xor(a[c], off);
    if (lane < 3) {
        const int c = lane;
        const float kk[4] = {1.f, 3.f, 3.f, 1.f};
        int sy = y & 1, sx = xx & 1;
        int u0 = ((y + sy) >> 1) - 1, v0 = ((xx + sx) >> 1) - 1;
        float cy0 = kk[sy], cy1 = kk[sy + 2], cx0 = kk[sx], cx1 = kk[sx + 2];
        float sk = 0.f;
        #pragma unroll
        for (int aa = 0; aa < 2; ++aa)
            #pragma unroll
            for (int bb = 0; bb < 2; ++bb) {
                int u = u0 + aa, vv = v0 + bb;
                if (u >= 0 && u < 32 && vv >= 0 && vv < 32)
                    sk += (aa ? cy1 : cy0) * (bb ? cx1 : cx0) *
                          skiprgb[(((size_t)b * 3 + c) * 32 + u) * 32 + vv];
            }
        sk *= (1.0f / 16.0f);
        out[(((size_t)b * 3 + c) * 64 + y) * 64 + xx] = a[c] + bias3[c] + sk;
    }
}

extern "C" void kernel_launch(void* const* d_in, const int* in_sizes, int n_in,
                              void* d_out, int out_size, void* d_ws, size_t ws_size,
                              hipStream_t stream)
{
    const float* x       = (const float*)d_in[0];
    const float* style   = (const float*)d_in[1];
    const float* skiprgb = (const float*)d_in[2];
    const float* noise1  = (const float*)d_in[3];
    const float* noise2  = (const float*)d_in[4];
    const float* w1      = (const float*)d_in[5];
    const float* m1w     = (const float*)d_in[6];
    const float* m1b     = (const float*)d_in[7];
    const float* bias1   = (const float*)d_in[8];
    const float* nw1     = (const float*)d_in[9];
    const float* w2      = (const float*)d_in[10];
    const float* m2w     = (const float*)d_in[11];
    const float* m2b     = (const float*)d_in[12];
    const float* bias2   = (const float*)d_in[13];
    const float* nw2     = (const float*)d_in[14];
    const float* w3      = (const float*)d_in[15];
    const float* m3w     = (const float*)d_in[16];
    const float* m3b     = (const float*)d_in[17];
    const float* bias3   = (const float*)d_in[18];
    float* out = (float*)d_out;

    char* p = (char*)d_ws;
    auto alloc = [&](size_t bytes) { char* r = p; p += (bytes + 255) & ~(size_t)255; return r; };
    float* s1 = (float*)alloc(8 * 512 * 4);
    float* s2 = (float*)alloc(8 * 512 * 4);
    float* s3 = (float*)alloc(8 * 512 * 4);
    float* d1 = (float*)alloc(8 * 512 * 4);
    float* d2 = (float*)alloc(8 * 512 * 4);
    f16* wA1 = (f16*)alloc((size_t)9 * 512 * 512 * 2);
    f16* wA2 = (f16*)alloc((size_t)9 * 512 * 512 * 2);
    // overlay region: [xm | ctp | in1], with in2 aliasing [xm|ctp] (both dead by then)
    const size_t XM_B  = (size_t)8 * 32 * 32 * 512 * 2;        // 8.39 MB
    const size_t CTP_B = (size_t)8 * 512 * 68 * 68 * 2;        // 37.88 MB
    const size_t IN1_B = (size_t)8 * 64 * 64 * 512 * 2;        // 33.55 MB
    char* ovl = (char*)alloc(XM_B + CTP_B + IN1_B);
    f16* xm  = (f16*)ovl;
    f16* ctp = (f16*)(ovl + XM_B);
    f16* in1 = (f16*)(ovl + XM_B + CTP_B);
    f16* in2 = (f16*)ovl;   // reuses xm+ctp space (46.3 MB >= 33.6 MB)

    hipMemsetAsync(ctp, 0, CTP_B, stream);   // halo zeros for conv1 output buffer
    k_styles<<<6, 256, 0, stream>>>(style, m1w, m1b, m2w, m2b, m3w, m3b, s1, s2, s3);
    k_demod<<<dim3(512, 2), 256, 0, stream>>>(w1, s1, d1, w2, s2, d2);
    k_prep_w<<<2048, 256, 0, stream>>>(w1, w2, wA1, wA2);
    k_prep_x<<<dim3(32, 8), 256, 0, stream>>>(x, s1, xm);
    k_conv1<<<dim3(4, 65, 16), 256, 0, stream>>>(xm, wA1, ctp);
    k_blur1<<<dim3(8, 64, 8), dim3(64, 4), 0, stream>>>(ctp, d1, noise1, nw1, bias1, s2, in1);
    k_conv2<<<dim3(8, 64, 8), 256, 0, stream>>>(in1, wA2, d2, noise2, nw2, bias2, s3, in2);
    k_rgb<<<8192, 256, 0, stream>>>(in2, w3, bias3, skiprgb, out);
}

// Round 2
// 668.194 us; speedup vs baseline: 2.2311x; 2.2311x over previous
//
#include <hip/hip_runtime.h>

typedef _Float16 f16;
typedef __attribute__((ext_vector_type(4))) _Float16 f16x4;
typedef __attribute__((ext_vector_type(8))) _Float16 f16x8;
typedef __attribute__((ext_vector_type(4))) float f32x4;

#define SC_CONV 0.014731391274719738f   /* 1/sqrt(512*9) */
#define SC_RGB  0.04419417382415922f    /* 1/sqrt(512)   */
#define SC_LIN  0.04419417382415922f    /* 1/sqrt(512)   */
#define SQRT2F  1.4142135623730951f

__device__ inline f16x8 zero_f16x8() {
    f16x8 v;
    #pragma unroll
    for (int i = 0; i < 8; ++i) v[i] = (_Float16)0.0f;
    return v;
}
__device__ inline f32x4 zero_f32x4() {
    f32x4 v;
    #pragma unroll
    for (int i = 0; i < 4; ++i) v[i] = 0.0f;
    return v;
}
__device__ inline void gload_lds16(const void* g, void* l) {
    __builtin_amdgcn_global_load_lds(
        (const __attribute__((address_space(1))) unsigned int*)g,
        (__attribute__((address_space(3))) unsigned int*)l, 16, 0, 0);
}

// ---------------- styles: s_k[b,o] = style[b,:] @ (mod_w*sc).T + mod_b ----------------
__global__ __launch_bounds__(256) void k_styles(
    const float* __restrict__ style,
    const float* __restrict__ m1w, const float* __restrict__ m1b,
    const float* __restrict__ m2w, const float* __restrict__ m2b,
    const float* __restrict__ m3w, const float* __restrict__ m3b,
    float* __restrict__ s1, float* __restrict__ s2, float* __restrict__ s3)
{
    int g = blockIdx.x * 256 + threadIdx.x;      // 0..1535
    int set = g >> 9, o = g & 511;
    const float* mw = set == 0 ? m1w : set == 1 ? m2w : m3w;
    const float* mb = set == 0 ? m1b : set == 1 ? m2b : m3b;
    float* out = set == 0 ? s1 : set == 1 ? s2 : s3;
    float acc[8] = {0,0,0,0,0,0,0,0};
    for (int i = 0; i < 512; ++i) {
        float w = mw[o * 512 + i];
        #pragma unroll
        for (int b = 0; b < 8; ++b) acc[b] += style[b * 512 + i] * w;
    }
    #pragma unroll
    for (int b = 0; b < 8; ++b) out[b * 512 + o] = acc[b] * SC_LIN + mb[o];
}

// ---------------- demod: d[b,o] = rsqrt(sc^2 * sum_i s[b,i]^2 * sum_t w[o,i,t]^2 + eps) ----
__global__ __launch_bounds__(256) void k_demod(
    const float* __restrict__ w1, const float* __restrict__ s1, float* __restrict__ d1,
    const float* __restrict__ w2, const float* __restrict__ s2, float* __restrict__ d2)
{
    const int o = blockIdx.x, set = blockIdx.y;
    const float* w = set ? w2 : w1;
    const float* s = set ? s2 : s1;
    float* d = set ? d2 : d1;
    float acc[8] = {0,0,0,0,0,0,0,0};
    for (int i = threadIdx.x; i < 512; i += 256) {
        const float* wp = w + ((size_t)o * 512 + i) * 9;
        float sw = 0.f;
        #pragma unroll
        for (int t = 0; t < 9; ++t) { float vv = wp[t]; sw += vv * vv; }
        #pragma unroll
        for (int b = 0; b < 8; ++b) { float sv = s[b * 512 + i]; acc[b] += sv * sv * sw; }
    }
    __shared__ float red[8][4];
    const int lane = threadIdx.x & 63, wid = threadIdx.x >> 6;
    #pragma unroll
    for (int b = 0; b < 8; ++b)
        #pragma unroll
        for (int off = 1; off < 64; off <<= 1)
            acc[b] += __shfl_xor(acc[b], off);
    if (lane == 0) {
        #pragma unroll
        for (int b = 0; b < 8; ++b) red[b][wid] = acc[b];
    }
    __syncthreads();
    if (threadIdx.x < 8) {
        float t = red[threadIdx.x][0] + red[threadIdx.x][1] + red[threadIdx.x][2] + red[threadIdx.x][3];
        d[threadIdx.x * 512 + o] = rsqrtf(t * (SC_CONV * SC_CONV) + 1e-8f);
    }
}

// ---------------- weight prep: wA[tap][o][i] = f16(w[o][i][tap]) ----------------
__global__ __launch_bounds__(256) void k_prep_w(
    const float* __restrict__ w1, const float* __restrict__ w2,
    f16* __restrict__ wA1, f16* __restrict__ wA2)
{
    int g = blockIdx.x * 256 + threadIdx.x;     // over 2*512*512
    int set = g >> 18; int oi = g & 262143;
    int o = oi >> 9, i = oi & 511;
    const float* w = (set ? w2 : w1) + (size_t)oi * 9;
    f16* wa = set ? wA2 : wA1;
    #pragma unroll
    for (int t = 0; t < 9; ++t)
        wa[((size_t)t * 512 + o) * 512 + i] = (f16)w[t];
}

// ---------------- x prep: xm[b][u][v][i] = f16(x[b,i,u,v] * s1[b,i] * sc) (NHWC) --------
__global__ __launch_bounds__(256) void k_prep_x(
    const float* __restrict__ x, const float* __restrict__ s1, f16* __restrict__ xm)
{
    int u = blockIdx.x, b = blockIdx.y;
    __shared__ float t[32][33];
    int tx = threadIdx.x & 31, ty = threadIdx.x >> 5;   // 32 x 8
    for (int ic = 0; ic < 512; ic += 32) {
        #pragma unroll
        for (int k = 0; k < 4; ++k) {
            int i = ic + ty + 8 * k;
            t[ty + 8 * k][tx] = x[(((size_t)b * 512 + i) * 32 + u) * 32 + tx];
        }
        __syncthreads();
        #pragma unroll
        for (int k = 0; k < 4; ++k) {
            int v = ty + 8 * k;
            int i = ic + tx;
            float sv = s1[b * 512 + i] * SC_CONV;
            xm[(((size_t)b * 32 + u) * 32 + v) * 512 + i] = (f16)(t[tx][v] * sv);
        }
        __syncthreads();
    }
}

// ---------------- conv1: 4-phase conv-transpose (stride2, 3x3) via MFMA -----------------
__global__ __launch_bounds__(256) void k_conv1(
    const f16* __restrict__ xm, const f16* __restrict__ wA1, f16* __restrict__ ctp)
{
    const int b = blockIdx.z >> 1, q = blockIdx.z & 1;
    const int m = blockIdx.y, p = m & 1, up = m >> 1;
    const int lane = threadIdx.x & 63, wid = threadIdx.x >> 6;
    const int oW = blockIdx.x * 128 + wid * 32;
    const int lr = lane & 15, lk = lane >> 4;
    f32x4 acc[2][3];
    #pragma unroll
    for (int a = 0; a < 2; ++a)
        #pragma unroll
        for (int c = 0; c < 3; ++c) acc[a][c] = zero_f32x4();
    const int nty = p ? 1 : 2, ntx = q ? 1 : 2;
    for (int ay = 0; ay < nty; ++ay) {
        int u = up - ay;
        if (u < 0 || u >= 32) continue;
        int ty = p + 2 * ay;
        const f16* xr = xm + ((size_t)b * 32 + u) * 32 * 512;
        for (int ax = 0; ax < ntx; ++ax) {
            int txp = q + 2 * ax;
            const f16* wt = wA1 + (size_t)(ty * 3 + txp) * 512 * 512;
            for (int ic = 0; ic < 512; ic += 32) {
                f16x8 af[2], bf[3];
                #pragma unroll
                for (int mt = 0; mt < 2; ++mt)
                    af[mt] = *(const f16x8*)(wt + (size_t)(oW + mt * 16 + lr) * 512 + ic + lk * 8);
                #pragma unroll
                for (int nt = 0; nt < 3; ++nt) {
                    int v = nt * 16 + lr - ax;
                    bf[nt] = (v >= 0 && v < 32)
                        ? *(const f16x8*)(xr + (size_t)v * 512 + ic + lk * 8)
                        : zero_f16x8();
                }
                #pragma unroll
                for (int mt = 0; mt < 2; ++mt)
                    #pragma unroll
                    for (int nt = 0; nt < 3; ++nt)
                        acc[mt][nt] = __builtin_amdgcn_mfma_f32_16x16x32_f16(
                            af[mt], bf[nt], acc[mt][nt], 0, 0, 0);
            }
        }
    }
    const int row = 1 + m;
    #pragma unroll
    for (int mt = 0; mt < 2; ++mt)
        #pragma unroll
        for (int nt = 0; nt < 3; ++nt) {
            int vp = nt * 16 + lr;
            if (vp >= 33 - q) continue;
            int col = 1 + 2 * vp + q;
            #pragma unroll
            for (int r = 0; r < 4; ++r) {
                int o = oW + mt * 16 + lk * 4 + r;
                ctp[(((size_t)b * 512 + o) * 68 + row) * 68 + col] = (f16)acc[mt][nt][r];
            }
        }
}

// ---------------- blur1 + demod + noise + bias + lrelu + next-layer modulation ----------
// writes NHWC f16 into halo'd in1h[b][66][66][512] (interior at +1,+1; halo pre-zeroed)
__global__ __launch_bounds__(256) void k_blur1(
    const f16* __restrict__ ctp, const float* __restrict__ d1,
    const float* __restrict__ noise1, const float* __restrict__ nw1,
    const float* __restrict__ bias1, const float* __restrict__ s2,
    f16* __restrict__ in1h)
{
    const int oB = blockIdx.x * 64, y = blockIdx.y, b = blockIdx.z;
    const int tx = threadIdx.x, ty = threadIdx.y;   // 64 x 4
    __shared__ f16 T[64][66];
    const float kk[4] = {1.f, 3.f, 3.f, 1.f};
    float nz = nw1[0] * noise1[((size_t)b * 64 + y) * 64 + tx];
    for (int oi = 0; oi < 16; ++oi) {
        int ol = oi * 4 + ty, o = oB + ol;
        const f16* base = ctp + (((size_t)b * 512 + o) * 68 + y) * 68 + tx;
        float s = 0.f;
        #pragma unroll
        for (int sr = 0; sr < 4; ++sr)
            #pragma unroll
            for (int tc = 0; tc < 4; ++tc)
                s += kk[sr] * kk[tc] * (float)base[sr * 68 + tc];
        s *= (1.0f / 16.0f);
        float v = s * d1[b * 512 + o] + nz + bias1[o];
        v = (v > 0.f ? v : 0.2f * v) * SQRT2F;
        v *= s2[b * 512 + o] * SC_CONV;
        T[ol][tx] = (f16)v;
    }
    __syncthreads();
    #pragma unroll
    for (int xi = 0; xi < 16; ++xi) {
        int xx = xi * 4 + ty;
        in1h[(((size_t)b * 66 + 1 + y) * 66 + 1 + xx) * 512 + oB + tx] = T[tx][xx];
    }
}

// ---------------- conv2: 128x128-tile implicit-GEMM, LDS-staged (m97 structure) ---------
// A = wA2[tap][o][i] (M=512 o), B = in1h NHWC halo'd (N=4096 pix/batch), K = 9*512
// LDS slot swizzle: 16B-slot s of row r holds global slot s ^ ((r>>1)&3)  (2-way free)
__global__ __launch_bounds__(256) void k_conv2(
    const f16* __restrict__ in1h, const f16* __restrict__ wA2,
    const float* __restrict__ d2, const float* __restrict__ noise2,
    const float* __restrict__ nw2, const float* __restrict__ bias2,
    const float* __restrict__ s3, f16* __restrict__ in2)
{
    const int b = blockIdx.z, mB = blockIdx.y * 128, nb = blockIdx.x;
    const int y0 = nb * 2;                 // 128 pixels = rows y0, y0+1
    __shared__ f16 Asm[128 * 32];
    __shared__ f16 Bsm[128 * 32];
    const int tid = threadIdx.x, lane = tid & 63, wid = tid >> 6;
    const int wm = wid >> 1, wn = wid & 1;
    const int lr = lane & 15, lk = lane >> 4;

    f32x4 acc[4][4];
    #pragma unroll
    for (int mt = 0; mt < 4; ++mt)
        #pragma unroll
        for (int nt = 0; nt < 4; ++nt) acc[mt][nt] = zero_f32x4();

    // staging: 512 16B-slots per tile; wave w covers chunks w*2, w*2+1 (64 slots each)
    const int idx0 = wid * 128 + lane;     // slot index, chunk 0
    const int idx1 = idx0 + 64;            // chunk 1
    const int rA0 = idx0 >> 2, sw0 = (idx0 & 3) ^ ((rA0 >> 1) & 3);
    const int rA1 = idx1 >> 2, sw1 = (idx1 & 3) ^ ((rA1 >> 1) & 3);
    const long aOff0 = (long)(mB + rA0) * 512 + sw0 * 8;
    const long aOff1 = (long)(mB + rA1) * 512 + sw1 * 8;
    const int py0 = y0 + (rA0 >> 6), px0 = rA0 & 63;
    const int py1 = y0 + (rA1 >> 6), px1 = rA1 & 63;
    const long bOff0 = ((long)(b * 66 + 1 + py0) * 66 + 1 + px0) * 512 + sw0 * 8;
    const long bOff1 = ((long)(b * 66 + 1 + py1) * 66 + 1 + px1) * 512 + sw1 * 8;
    char* aDst0 = (char*)Asm + (wid * 2 + 0) * 1024;
    char* aDst1 = (char*)Asm + (wid * 2 + 1) * 1024;
    char* bDst0 = (char*)Bsm + (wid * 2 + 0) * 1024;
    char* bDst1 = (char*)Bsm + (wid * 2 + 1) * 1024;

    // ds_read byte addresses (lane-constant)
    int raddrA[4], raddrB[4];
    #pragma unroll
    for (int mt = 0; mt < 4; ++mt) {
        int R = wm * 64 + mt * 16 + lr;
        raddrA[mt] = R * 64 + ((lk ^ ((R >> 1) & 3)) * 16);
    }
    #pragma unroll
    for (int nt = 0; nt < 4; ++nt) {
        int R = wn * 64 + nt * 16 + lr;
        raddrB[nt] = R * 64 + ((lk ^ ((R >> 1) & 3)) * 16);
    }

    for (int tap = 0; tap < 9; ++tap) {
        const int dy = tap / 3 - 1, dx = tap % 3 - 1;
        const f16* wt = wA2 + (size_t)tap * 512 * 512;
        const long doff = (long)(dy * 66 + dx) * 512;
        for (int ic = 0; ic < 512; ic += 32) {
            gload_lds16(wt + aOff0 + ic, aDst0);
            gload_lds16(wt + aOff1 + ic, aDst1);
            gload_lds16(in1h + bOff0 + doff + ic, bDst0);
            gload_lds16(in1h + bOff1 + doff + ic, bDst1);
            __syncthreads();
            f16x8 af[4], bf[4];
            #pragma unroll
            for (int mt = 0; mt < 4; ++mt)
                af[mt] = *(const f16x8*)((const char*)Asm + raddrA[mt]);
            #pragma unroll
            for (int nt = 0; nt < 4; ++nt)
                bf[nt] = *(const f16x8*)((const char*)Bsm + raddrB[nt]);
            #pragma unroll
            for (int mt = 0; mt < 4; ++mt)
                #pragma unroll
                for (int nt = 0; nt < 4; ++nt)
                    acc[mt][nt] = __builtin_amdgcn_mfma_f32_16x16x32_f16(
                        af[mt], bf[nt], acc[mt][nt], 0, 0, 0);
            __syncthreads();
        }
    }

    // epilogue: demod + noise + bias + lrelu + s3*SC_RGB, NHWC f16x4 stores
    const float* d2b = d2 + b * 512;
    const float* s3b = s3 + b * 512;
    const float nw = nw2[0];
    #pragma unroll
    for (int mt = 0; mt < 4; ++mt) {
        const int ob = mB + wm * 64 + mt * 16 + lk * 4;
        const float4 dv = *(const float4*)(d2b + ob);
        const float4 bv = *(const float4*)(bias2 + ob);
        const float4 sv = *(const float4*)(s3b + ob);
        const float dd[4] = {dv.x, dv.y, dv.z, dv.w};
        const float bb[4] = {bv.x, bv.y, bv.z, bv.w};
        const float ss[4] = {sv.x, sv.y, sv.z, sv.w};
        #pragma unroll
        for (int nt = 0; nt < 4; ++nt) {
            const int c = wn * 64 + nt * 16 + lr;
            const int py = y0 + (c >> 6), px = c & 63;
            const float nz = nw * noise2[((size_t)b * 64 + py) * 64 + px];
            f16x4 st;
            #pragma unroll
            for (int r = 0; r < 4; ++r) {
                float v = acc[mt][nt][r] * dd[r] + nz + bb[r];
                v = (v > 0.f ? v : 0.2f * v) * SQRT2F;
                v *= ss[r] * SC_RGB;
                st[r] = (f16)v;
            }
            *(f16x4*)(in2 + (((size_t)b * 64 + py) * 64 + px) * 512 + ob) = st;
        }
    }
}

// ---------------- ToRGB: wave-per-pixel dot over 512 ch + bias + skip upfirdn -----------
__global__ __launch_bounds__(256) void k_rgb(
    const f16* __restrict__ in2, const float* __restrict__ w3,
    const float* __restrict__ bias3, const float* __restrict__ skiprgb,
    float* __restrict__ out)
{
    const int wid = threadIdx.x >> 6, lane = threadIdx.x & 63;
    const int pix = blockIdx.x * 4 + wid;            // 0..32767
    const int b = pix >> 12, rem = pix & 4095, y = rem >> 6, xx = rem & 63;
    const f16* ip = in2 + (size_t)pix * 512 + lane * 8;
    f16x8 v = *(const f16x8*)ip;
    float a[3] = {0.f, 0.f, 0.f};
    const float* wp = w3 + lane * 8;
    #pragma unroll
    for (int e = 0; e < 8; ++e) {
        float xv = (float)v[e];
        a[0] += xv * wp[e];
        a[1] += xv * wp[512 + e];
        a[2] += xv * wp[1024 + e];
    }
    #pragma unroll
    for (int c = 0; c < 3; ++c)
        #pragma unroll
        for (int off = 1; off < 64; off <<= 1)
            a[c] += __shfl_xor(a[c], off);
    if (lane < 3) {
        const int c = lane;
        const float kk[4] = {1.f, 3.f, 3.f, 1.f};
        int sy = y & 1, sx = xx & 1;
        int u0 = ((y + sy) >> 1) - 1, v0 = ((xx + sx) >> 1) - 1;
        float cy0 = kk[sy], cy1 = kk[sy + 2], cx0 = kk[sx], cx1 = kk[sx + 2];
        float sk = 0.f;
        #pragma unroll
        for (int aa = 0; aa < 2; ++aa)
            #pragma unroll
            for (int bb = 0; bb < 2; ++bb) {
                int u = u0 + aa, vv = v0 + bb;
                if (u >= 0 && u < 32 && vv >= 0 && vv < 32)
                    sk += (aa ? cy1 : cy0) * (bb ? cx1 : cx0) *
                          skiprgb[(((size_t)b * 3 + c) * 32 + u) * 32 + vv];
            }
        sk *= (1.0f / 16.0f);
        out[(((size_t)b * 3 + c) * 64 + y) * 64 + xx] = a[c] + bias3[c] + sk;
    }
}

extern "C" void kernel_launch(void* const* d_in, const int* in_sizes, int n_in,
                              void* d_out, int out_size, void* d_ws, size_t ws_size,
                              hipStream_t stream)
{
    const float* x       = (const float*)d_in[0];
    const float* style   = (const float*)d_in[1];
    const float* skiprgb = (const float*)d_in[2];
    const float* noise1  = (const float*)d_in[3];
    const float* noise2  = (const float*)d_in[4];
    const float* w1      = (const float*)d_in[5];
    const float* m1w     = (const float*)d_in[6];
    const float* m1b     = (const float*)d_in[7];
    const float* bias1   = (const float*)d_in[8];
    const float* nw1     = (const float*)d_in[9];
    const float* w2      = (const float*)d_in[10];
    const float* m2w     = (const float*)d_in[11];
    const float* m2b     = (const float*)d_in[12];
    const float* bias2   = (const float*)d_in[13];
    const float* nw2     = (const float*)d_in[14];
    const float* w3      = (const float*)d_in[15];
    const float* m3w     = (const float*)d_in[16];
    const float* m3b     = (const float*)d_in[17];
    const float* bias3   = (const float*)d_in[18];
    float* out = (float*)d_out;

    char* p = (char*)d_ws;
    auto alloc = [&](size_t bytes) { char* r = p; p += (bytes + 255) & ~(size_t)255; return r; };
    float* s1 = (float*)alloc(8 * 512 * 4);
    float* s2 = (float*)alloc(8 * 512 * 4);
    float* s3 = (float*)alloc(8 * 512 * 4);
    float* d1 = (float*)alloc(8 * 512 * 4);
    float* d2 = (float*)alloc(8 * 512 * 4);
    f16* wA1 = (f16*)alloc((size_t)9 * 512 * 512 * 2);
    f16* wA2 = (f16*)alloc((size_t)9 * 512 * 512 * 2);
    // overlay region: [xm | ctp | in1h], with in2 aliasing [xm|ctp] (both dead by then)
    const size_t XM_B   = (size_t)8 * 32 * 32 * 512 * 2;        // 8.39 MB
    const size_t CTP_B  = (size_t)8 * 512 * 68 * 68 * 2;        // 37.88 MB
    const size_t IN1H_B = (size_t)8 * 66 * 66 * 512 * 2;        // 35.69 MB
    char* ovl = (char*)alloc(XM_B + CTP_B + IN1H_B);
    f16* xm   = (f16*)ovl;
    f16* ctp  = (f16*)(ovl + XM_B);
    f16* in1h = (f16*)(ovl + XM_B + CTP_B);
    f16* in2  = (f16*)ovl;   // reuses xm+ctp space (46.3 MB >= 33.6 MB)

    hipMemsetAsync(ctp, 0, CTP_B, stream);    // halo zeros for conv1 output buffer
    hipMemsetAsync(in1h, 0, IN1H_B, stream);  // halo zeros for conv2 input buffer
    k_styles<<<6, 256, 0, stream>>>(style, m1w, m1b, m2w, m2b, m3w, m3b, s1, s2, s3);
    k_demod<<<dim3(512, 2), 256, 0, stream>>>(w1, s1, d1, w2, s2, d2);
    k_prep_w<<<2048, 256, 0, stream>>>(w1, w2, wA1, wA2);
    k_prep_x<<<dim3(32, 8), 256, 0, stream>>>(x, s1, xm);
    k_conv1<<<dim3(4, 65, 16), 256, 0, stream>>>(xm, wA1, ctp);
    k_blur1<<<dim3(8, 64, 8), dim3(64, 4), 0, stream>>>(ctp, d1, noise1, nw1, bias1, s2, in1h);
    k_conv2<<<dim3(32, 4, 8), 256, 0, stream>>>(in1h, wA2, d2, noise2, nw2, bias2, s3, in2);
    k_rgb<<<8192, 256, 0, stream>>>(in2, w3, bias3, skiprgb, out);
}

// Round 3
// 472.646 us; speedup vs baseline: 3.1542x; 1.4137x over previous
//
#include <hip/hip_runtime.h>

typedef _Float16 f16;
typedef __attribute__((ext_vector_type(4))) _Float16 f16x4;
typedef __attribute__((ext_vector_type(8))) _Float16 f16x8;
typedef __attribute__((ext_vector_type(4))) float f32x4;

#define SC_CONV 0.014731391274719738f   /* 1/sqrt(512*9) */
#define SC_RGB  0.04419417382415922f    /* 1/sqrt(512)   */
#define SC_LIN  0.04419417382415922f    /* 1/sqrt(512)   */
#define SQRT2F  1.4142135623730951f

__device__ inline f16x8 zero_f16x8() {
    f16x8 v;
    #pragma unroll
    for (int i = 0; i < 8; ++i) v[i] = (_Float16)0.0f;
    return v;
}
__device__ inline f32x4 zero_f32x4() {
    f32x4 v;
    #pragma unroll
    for (int i = 0; i < 4; ++i) v[i] = 0.0f;
    return v;
}
__device__ inline void gload_lds16(const void* g, void* l) {
    __builtin_amdgcn_global_load_lds(
        (const __attribute__((address_space(1))) unsigned int*)g,
        (__attribute__((address_space(3))) unsigned int*)l, 16, 0, 0);
}

// ---------------- styles: s_k[b,o] = style[b,:] @ (mod_w*sc).T + mod_b ----------------
__global__ __launch_bounds__(256) void k_styles(
    const float* __restrict__ style,
    const float* __restrict__ m1w, const float* __restrict__ m1b,
    const float* __restrict__ m2w, const float* __restrict__ m2b,
    const float* __restrict__ m3w, const float* __restrict__ m3b,
    float* __restrict__ s1, float* __restrict__ s2, float* __restrict__ s3)
{
    int g = blockIdx.x * 256 + threadIdx.x;      // 0..1535
    int set = g >> 9, o = g & 511;
    const float* mw = set == 0 ? m1w : set == 1 ? m2w : m3w;
    const float* mb = set == 0 ? m1b : set == 1 ? m2b : m3b;
    float* out = set == 0 ? s1 : set == 1 ? s2 : s3;
    float acc[8] = {0,0,0,0,0,0,0,0};
    for (int i = 0; i < 512; ++i) {
        float w = mw[o * 512 + i];
        #pragma unroll
        for (int b = 0; b < 8; ++b) acc[b] += style[b * 512 + i] * w;
    }
    #pragma unroll
    for (int b = 0; b < 8; ++b) out[b * 512 + o] = acc[b] * SC_LIN + mb[o];
}

// ---------------- demod ----------------
__global__ __launch_bounds__(256) void k_demod(
    const float* __restrict__ w1, const float* __restrict__ s1, float* __restrict__ d1,
    const float* __restrict__ w2, const float* __restrict__ s2, float* __restrict__ d2)
{
    const int o = blockIdx.x, set = blockIdx.y;
    const float* w = set ? w2 : w1;
    const float* s = set ? s2 : s1;
    float* d = set ? d2 : d1;
    float acc[8] = {0,0,0,0,0,0,0,0};
    for (int i = threadIdx.x; i < 512; i += 256) {
        const float* wp = w + ((size_t)o * 512 + i) * 9;
        float sw = 0.f;
        #pragma unroll
        for (int t = 0; t < 9; ++t) { float vv = wp[t]; sw += vv * vv; }
        #pragma unroll
        for (int b = 0; b < 8; ++b) { float sv = s[b * 512 + i]; acc[b] += sv * sv * sw; }
    }
    __shared__ float red[8][4];
    const int lane = threadIdx.x & 63, wid = threadIdx.x >> 6;
    #pragma unroll
    for (int b = 0; b < 8; ++b)
        #pragma unroll
        for (int off = 1; off < 64; off <<= 1)
            acc[b] += __shfl_xor(acc[b], off);
    if (lane == 0) {
        #pragma unroll
        for (int b = 0; b < 8; ++b) red[b][wid] = acc[b];
    }
    __syncthreads();
    if (threadIdx.x < 8) {
        float t = red[threadIdx.x][0] + red[threadIdx.x][1] + red[threadIdx.x][2] + red[threadIdx.x][3];
        d[threadIdx.x * 512 + o] = rsqrtf(t * (SC_CONV * SC_CONV) + 1e-8f);
    }
}

// ---------------- weight prep: wA[tap][o][i] = f16(w[o][i][tap]) ----------------
__global__ __launch_bounds__(256) void k_prep_w(
    const float* __restrict__ w1, const float* __restrict__ w2,
    f16* __restrict__ wA1, f16* __restrict__ wA2)
{
    int g = blockIdx.x * 256 + threadIdx.x;     // over 2*512*512
    int set = g >> 18; int oi = g & 262143;
    const float* w = (set ? w2 : w1) + (size_t)oi * 9;
    f16* wa = set ? wA2 : wA1;
    int o = oi >> 9, i = oi & 511;
    #pragma unroll
    for (int t = 0; t < 9; ++t)
        wa[((size_t)t * 512 + o) * 512 + i] = (f16)w[t];
}

// ---------------- x prep: xmh[b][u+1][v+1][i] = f16(x[b,i,u,v] * s1[b,i] * sc) ---------
__global__ __launch_bounds__(256) void k_prep_x(
    const float* __restrict__ x, const float* __restrict__ s1, f16* __restrict__ xmh)
{
    int u = blockIdx.x, b = blockIdx.y;
    __shared__ float t[32][33];
    int tx = threadIdx.x & 31, ty = threadIdx.x >> 5;   // 32 x 8
    for (int ic = 0; ic < 512; ic += 32) {
        #pragma unroll
        for (int k = 0; k < 4; ++k) {
            int i = ic + ty + 8 * k;
            t[ty + 8 * k][tx] = x[(((size_t)b * 512 + i) * 32 + u) * 32 + tx];
        }
        __syncthreads();
        #pragma unroll
        for (int k = 0; k < 4; ++k) {
            int v = ty + 8 * k;
            int i = ic + tx;
            float sv = s1[b * 512 + i] * SC_CONV;
            xmh[(((size_t)b * 34 + u + 1) * 34 + v + 1) * 512 + i] = (f16)(t[tx][v] * sv);
        }
        __syncthreads();
    }
}

// ---------------- conv1: staged 4-phase conv-transpose (m97 structure) ------------------
// phase (p,q): GEMM M=512(o), N = Mm*Nn positions (u',v'), K = 512*ntaps
// tap (ay,ax): weight (ty,tx)=(p+2ay, q+2ax), B at xmh(u'+1-ay, v'+1-ax)
// writes ctp[b][o][1+2u'+p][1+2v'+q] (CHW 68x68 halo, borders pre-zeroed)
__global__ __launch_bounds__(256) void k_conv1s(
    const f16* __restrict__ xmh, const f16* __restrict__ wA1, f16* __restrict__ ctp)
{
    const int bz = blockIdx.z, b = bz >> 2, ph = bz & 3;
    const int p = ph >> 1, q = ph & 1;
    const int Nn = q ? 32 : 33;
    const int npos = (p ? 32 : 33) * Nn;
    const int posB = blockIdx.x * 128;
    if (posB >= npos) return;
    const int nt_x = q ? 1 : 2;
    const int ntaps = (p ? 1 : 2) * nt_x;
    const int mB = blockIdx.y * 128;

    __shared__ f16 Asm[128 * 32];
    __shared__ f16 Bsm[128 * 32];
    const int tid = threadIdx.x, lane = tid & 63, wid = tid >> 6;
    const int wm = wid >> 1, wn = wid & 1;
    const int lr = lane & 15, lk = lane >> 4;

    f32x4 acc[4][4];
    #pragma unroll
    for (int mt = 0; mt < 4; ++mt)
        #pragma unroll
        for (int nt = 0; nt < 4; ++nt) acc[mt][nt] = zero_f32x4();

    // staging slots
    const int idx0 = wid * 128 + lane, idx1 = idx0 + 64;
    const int rA0 = idx0 >> 2, sw0 = (idx0 & 3) ^ ((rA0 >> 1) & 3);
    const int rA1 = idx1 >> 2, sw1 = (idx1 & 3) ^ ((rA1 >> 1) & 3);
    const long aOff0 = (long)(mB + rA0) * 512 + sw0 * 8;
    const long aOff1 = (long)(mB + rA1) * 512 + sw1 * 8;
    // B positions (clamped for partial tiles)
    int pos0 = posB + rA0; if (pos0 > npos - 1) pos0 = npos - 1;
    int pos1 = posB + rA1; if (pos1 > npos - 1) pos1 = npos - 1;
    int u0, v0, u1, v1;
    if (q) { u0 = pos0 >> 5; v0 = pos0 & 31; u1 = pos1 >> 5; v1 = pos1 & 31; }
    else   { u0 = (unsigned)pos0 / 33u; v0 = pos0 - u0 * 33;
             u1 = (unsigned)pos1 / 33u; v1 = pos1 - u1 * 33; }
    const long bBase0 = ((long)(b * 34 + u0 + 1) * 34 + v0 + 1) * 512 + sw0 * 8;
    const long bBase1 = ((long)(b * 34 + u1 + 1) * 34 + v1 + 1) * 512 + sw1 * 8;
    char* aDst0 = (char*)Asm + (wid * 2 + 0) * 1024;
    char* aDst1 = (char*)Asm + (wid * 2 + 1) * 1024;
    char* bDst0 = (char*)Bsm + (wid * 2 + 0) * 1024;
    char* bDst1 = (char*)Bsm + (wid * 2 + 1) * 1024;

    int raddrA[4], raddrB[4];
    #pragma unroll
    for (int mt = 0; mt < 4; ++mt) {
        int R = wm * 64 + mt * 16 + lr;
        raddrA[mt] = R * 64 + ((lk ^ ((R >> 1) & 3)) * 16);
    }
    #pragma unroll
    for (int nt = 0; nt < 4; ++nt) {
        int R = wn * 64 + nt * 16 + lr;
        raddrB[nt] = R * 64 + ((lk ^ ((R >> 1) & 3)) * 16);
    }

    for (int t = 0; t < ntaps; ++t) {
        const int ay = (nt_x == 2) ? (t >> 1) : t;
        const int ax = (nt_x == 2) ? (t & 1) : 0;
        const f16* wt = wA1 + (size_t)((p + 2 * ay) * 3 + (q + 2 * ax)) * 512 * 512;
        const long doff = -(long)(ay * 34 + ax) * 512;
        for (int ic = 0; ic < 512; ic += 32) {
            gload_lds16(wt + aOff0 + ic, aDst0);
            gload_lds16(wt + aOff1 + ic, aDst1);
            gload_lds16(xmh + bBase0 + doff + ic, bDst0);
            gload_lds16(xmh + bBase1 + doff + ic, bDst1);
            __syncthreads();
            f16x8 af[4], bf[4];
            #pragma unroll
            for (int mt = 0; mt < 4; ++mt)
                af[mt] = *(const f16x8*)((const char*)Asm + raddrA[mt]);
            #pragma unroll
            for (int nt = 0; nt < 4; ++nt)
                bf[nt] = *(const f16x8*)((const char*)Bsm + raddrB[nt]);
            #pragma unroll
            for (int mt = 0; mt < 4; ++mt)
                #pragma unroll
                for (int nt = 0; nt < 4; ++nt)
                    acc[mt][nt] = __builtin_amdgcn_mfma_f32_16x16x32_f16(
                        af[mt], bf[nt], acc[mt][nt], 0, 0, 0);
            __syncthreads();
        }
    }

    // epilogue: scatter f16 to ctp interior
    #pragma unroll
    for (int nt = 0; nt < 4; ++nt) {
        const int c = wn * 64 + nt * 16 + lr;
        const int pos = posB + c;
        if (pos >= npos) continue;
        int up, vp;
        if (q) { up = pos >> 5; vp = pos & 31; }
        else   { up = (unsigned)pos / 33u; vp = pos - up * 33; }
        const int row = 1 + 2 * up + p, col = 1 + 2 * vp + q;
        f16* dst = ctp + ((size_t)b * 512 * 68 + row) * 68 + col;
        #pragma unroll
        for (int mt = 0; mt < 4; ++mt) {
            const int ob = mB + wm * 64 + mt * 16 + lk * 4;
            #pragma unroll
            for (int r = 0; r < 4; ++r)
                dst[(size_t)(ob + r) * 68 * 68] = (f16)acc[mt][nt][r];
        }
    }
}

// ---------------- blur1 + demod + noise + bias + lrelu + next-layer modulation ----------
__global__ __launch_bounds__(256) void k_blur1(
    const f16* __restrict__ ctp, const float* __restrict__ d1,
    const float* __restrict__ noise1, const float* __restrict__ nw1,
    const float* __restrict__ bias1, const float* __restrict__ s2,
    f16* __restrict__ in1h)
{
    const int oB = blockIdx.x * 64, y = blockIdx.y, b = blockIdx.z;
    const int tx = threadIdx.x, ty = threadIdx.y;   // 64 x 4
    __shared__ f16 T[64][66];
    const float kk[4] = {1.f, 3.f, 3.f, 1.f};
    float nz = nw1[0] * noise1[((size_t)b * 64 + y) * 64 + tx];
    for (int oi = 0; oi < 16; ++oi) {
        int ol = oi * 4 + ty, o = oB + ol;
        const f16* base = ctp + (((size_t)b * 512 + o) * 68 + y) * 68 + tx;
        float s = 0.f;
        #pragma unroll
        for (int sr = 0; sr < 4; ++sr)
            #pragma unroll
            for (int tc = 0; tc < 4; ++tc)
                s += kk[sr] * kk[tc] * (float)base[sr * 68 + tc];
        s *= (1.0f / 16.0f);
        float v = s * d1[b * 512 + o] + nz + bias1[o];
        v = (v > 0.f ? v : 0.2f * v) * SQRT2F;
        v *= s2[b * 512 + o] * SC_CONV;
        T[ol][tx] = (f16)v;
    }
    __syncthreads();
    #pragma unroll
    for (int xi = 0; xi < 16; ++xi) {
        int xx = xi * 4 + ty;
        in1h[(((size_t)b * 66 + 1 + y) * 66 + 1 + xx) * 512 + oB + tx] = T[tx][xx];
    }
}

// ---------------- conv2: 128x128-tile implicit-GEMM, LDS-staged ----------------
__global__ __launch_bounds__(256) void k_conv2(
    const f16* __restrict__ in1h, const f16* __restrict__ wA2,
    const float* __restrict__ d2, const float* __restrict__ noise2,
    const float* __restrict__ nw2, const float* __restrict__ bias2,
    const float* __restrict__ s3, f16* __restrict__ in2)
{
    const int b = blockIdx.z, mB = blockIdx.y * 128, nb = blockIdx.x;
    const int y0 = nb * 2;                 // 128 pixels = rows y0, y0+1
    __shared__ f16 Asm[128 * 32];
    __shared__ f16 Bsm[128 * 32];
    const int tid = threadIdx.x, lane = tid & 63, wid = tid >> 6;
    const int wm = wid >> 1, wn = wid & 1;
    const int lr = lane & 15, lk = lane >> 4;

    f32x4 acc[4][4];
    #pragma unroll
    for (int mt = 0; mt < 4; ++mt)
        #pragma unroll
        for (int nt = 0; nt < 4; ++nt) acc[mt][nt] = zero_f32x4();

    const int idx0 = wid * 128 + lane;
    const int idx1 = idx0 + 64;
    const int rA0 = idx0 >> 2, sw0 = (idx0 & 3) ^ ((rA0 >> 1) & 3);
    const int rA1 = idx1 >> 2, sw1 = (idx1 & 3) ^ ((rA1 >> 1) & 3);
    const long aOff0 = (long)(mB + rA0) * 512 + sw0 * 8;
    const long aOff1 = (long)(mB + rA1) * 512 + sw1 * 8;
    const int py0 = y0 + (rA0 >> 6), px0 = rA0 & 63;
    const int py1 = y0 + (rA1 >> 6), px1 = rA1 & 63;
    const long bOff0 = ((long)(b * 66 + 1 + py0) * 66 + 1 + px0) * 512 + sw0 * 8;
    const long bOff1 = ((long)(b * 66 + 1 + py1) * 66 + 1 + px1) * 512 + sw1 * 8;
    char* aDst0 = (char*)Asm + (wid * 2 + 0) * 1024;
    char* aDst1 = (char*)Asm + (wid * 2 + 1) * 1024;
    char* bDst0 = (char*)Bsm + (wid * 2 + 0) * 1024;
    char* bDst1 = (char*)Bsm + (wid * 2 + 1) * 1024;

    int raddrA[4], raddrB[4];
    #pragma unroll
    for (int mt = 0; mt < 4; ++mt) {
        int R = wm * 64 + mt * 16 + lr;
        raddrA[mt] = R * 64 + ((lk ^ ((R >> 1) & 3)) * 16);
    }
    #pragma unroll
    for (int nt = 0; nt < 4; ++nt) {
        int R = wn * 64 + nt * 16 + lr;
        raddrB[nt] = R * 64 + ((lk ^ ((R >> 1) & 3)) * 16);
    }

    for (int tap = 0; tap < 9; ++tap) {
        const int dy = tap / 3 - 1, dx = tap % 3 - 1;
        const f16* wt = wA2 + (size_t)tap * 512 * 512;
        const long doff = (long)(dy * 66 + dx) * 512;
        for (int ic = 0; ic < 512; ic += 32) {
            gload_lds16(wt + aOff0 + ic, aDst0);
            gload_lds16(wt + aOff1 + ic, aDst1);
            gload_lds16(in1h + bOff0 + doff + ic, bDst0);
            gload_lds16(in1h + bOff1 + doff + ic, bDst1);
            __syncthreads();
            f16x8 af[4], bf[4];
            #pragma unroll
            for (int mt = 0; mt < 4; ++mt)
                af[mt] = *(const f16x8*)((const char*)Asm + raddrA[mt]);
            #pragma unroll
            for (int nt = 0; nt < 4; ++nt)
                bf[nt] = *(const f16x8*)((const char*)Bsm + raddrB[nt]);
            #pragma unroll
            for (int mt = 0; mt < 4; ++mt)
                #pragma unroll
                for (int nt = 0; nt < 4; ++nt)
                    acc[mt][nt] = __builtin_amdgcn_mfma_f32_16x16x32_f16(
                        af[mt], bf[nt], acc[mt][nt], 0, 0, 0);
            __syncthreads();
        }
    }

    const float* d2b = d2 + b * 512;
    const float* s3b = s3 + b * 512;
    const float nw = nw2[0];
    #pragma unroll
    for (int mt = 0; mt < 4; ++mt) {
        const int ob = mB + wm * 64 + mt * 16 + lk * 4;
        const float4 dv = *(const float4*)(d2b + ob);
        const float4 bv = *(const float4*)(bias2 + ob);
        const float4 sv = *(const float4*)(s3b + ob);
        const float dd[4] = {dv.x, dv.y, dv.z, dv.w};
        const float bb[4] = {bv.x, bv.y, bv.z, bv.w};
        const float ss[4] = {sv.x, sv.y, sv.z, sv.w};
        #pragma unroll
        for (int nt = 0; nt < 4; ++nt) {
            const int c = wn * 64 + nt * 16 + lr;
            const int py = y0 + (c >> 6), px = c & 63;
            const float nz = nw * noise2[((size_t)b * 64 + py) * 64 + px];
            f16x4 st;
            #pragma unroll
            for (int r = 0; r < 4; ++r) {
                float v = acc[mt][nt][r] * dd[r] + nz + bb[r];
                v = (v > 0.f ? v : 0.2f * v) * SQRT2F;
                v *= ss[r] * SC_RGB;
                st[r] = (f16)v;
            }
            *(f16x4*)(in2 + (((size_t)b * 64 + py) * 64 + px) * 512 + ob) = st;
        }
    }
}

// ---------------- ToRGB ----------------
__global__ __launch_bounds__(256) void k_rgb(
    const f16* __restrict__ in2, const float* __restrict__ w3,
    const float* __restrict__ bias3, const float* __restrict__ skiprgb,
    float* __restrict__ out)
{
    const int wid = threadIdx.x >> 6, lane = threadIdx.x & 63;
    const int pix = blockIdx.x * 4 + wid;            // 0..32767
    const int b = pix >> 12, rem = pix & 4095, y = rem >> 6, xx = rem & 63;
    const f16* ip = in2 + (size_t)pix * 512 + lane * 8;
    f16x8 v = *(const f16x8*)ip;
    float a[3] = {0.f, 0.f, 0.f};
    const float* wp = w3 + lane * 8;
    #pragma unroll
    for (int e = 0; e < 8; ++e) {
        float xv = (float)v[e];
        a[0] += xv * wp[e];
        a[1] += xv * wp[512 + e];
        a[2] += xv * wp[1024 + e];
    }
    #pragma unroll
    for (int c = 0; c < 3; ++c)
        #pragma unroll
        for (int off = 1; off < 64; off <<= 1)
            a[c] += __shfl_xor(a[c], off);
    if (lane < 3) {
        const int c = lane;
        const float kk[4] = {1.f, 3.f, 3.f, 1.f};
        int sy = y & 1, sx = xx & 1;
        int u0 = ((y + sy) >> 1) - 1, v0 = ((xx + sx) >> 1) - 1;
        float cy0 = kk[sy], cy1 = kk[sy + 2], cx0 = kk[sx], cx1 = kk[sx + 2];
        float sk = 0.f;
        #pragma unroll
        for (int aa = 0; aa < 2; ++aa)
            #pragma unroll
            for (int bb = 0; bb < 2; ++bb) {
                int u = u0 + aa, vv = v0 + bb;
                if (u >= 0 && u < 32 && vv >= 0 && vv < 32)
                    sk += (aa ? cy1 : cy0) * (bb ? cx1 : cx0) *
                          skiprgb[(((size_t)b * 3 + c) * 32 + u) * 32 + vv];
            }
        sk *= (1.0f / 16.0f);
        out[(((size_t)b * 3 + c) * 64 + y) * 64 + xx] = a[c] + bias3[c] + sk;
    }
}

extern "C" void kernel_launch(void* const* d_in, const int* in_sizes, int n_in,
                              void* d_out, int out_size, void* d_ws, size_t ws_size,
                              hipStream_t stream)
{
    const float* x       = (const float*)d_in[0];
    const float* style   = (const float*)d_in[1];
    const float* skiprgb = (const float*)d_in[2];
    const float* noise1  = (const float*)d_in[3];
    const float* noise2  = (const float*)d_in[4];
    const float* w1      = (const float*)d_in[5];
    const float* m1w     = (const float*)d_in[6];
    const float* m1b     = (const float*)d_in[7];
    const float* bias1   = (const float*)d_in[8];
    const float* nw1     = (const float*)d_in[9];
    const float* w2      = (const float*)d_in[10];
    const float* m2w     = (const float*)d_in[11];
    const float* m2b     = (const float*)d_in[12];
    const float* bias2   = (const float*)d_in[13];
    const float* nw2     = (const float*)d_in[14];
    const float* w3      = (const float*)d_in[15];
    const float* m3w     = (const float*)d_in[16];
    const float* m3b     = (const float*)d_in[17];
    const float* bias3   = (const float*)d_in[18];
    float* out = (float*)d_out;

    char* p = (char*)d_ws;
    auto alloc = [&](size_t bytes) { char* r = p; p += (bytes + 255) & ~(size_t)255; return r; };
    float* s1 = (float*)alloc(8 * 512 * 4);
    float* s2 = (float*)alloc(8 * 512 * 4);
    float* s3 = (float*)alloc(8 * 512 * 4);
    float* d1 = (float*)alloc(8 * 512 * 4);
    float* d2 = (float*)alloc(8 * 512 * 4);
    f16* wA1 = (f16*)alloc((size_t)9 * 512 * 512 * 2);
    f16* wA2 = (f16*)alloc((size_t)9 * 512 * 512 * 2);
    // overlay region: [xmh | ctp | in1h], with in2 aliasing [xmh|ctp] (both dead by then)
    const size_t XMH_B  = (size_t)8 * 34 * 34 * 512 * 2;        //  9.47 MB
    const size_t CTP_B  = (size_t)8 * 512 * 68 * 68 * 2;        // 37.88 MB
    const size_t IN1H_B = (size_t)8 * 66 * 66 * 512 * 2;        // 35.69 MB
    char* ovl = (char*)alloc(XMH_B + CTP_B + IN1H_B);
    f16* xmh  = (f16*)ovl;
    f16* ctp  = (f16*)(ovl + XMH_B);
    f16* in1h = (f16*)(ovl + XMH_B + CTP_B);
    f16* in2  = (f16*)ovl;   // reuses xmh+ctp space (47.3 MB >= 33.6 MB)

    hipMemsetAsync(xmh, 0, XMH_B, stream);    // halo zeros for conv1 input
    hipMemsetAsync(ctp, 0, CTP_B, stream);    // halo zeros for conv1 output buffer
    hipMemsetAsync(in1h, 0, IN1H_B, stream);  // halo zeros for conv2 input buffer
    k_styles<<<6, 256, 0, stream>>>(style, m1w, m1b, m2w, m2b, m3w, m3b, s1, s2, s3);
    k_demod<<<dim3(512, 2), 256, 0, stream>>>(w1, s1, d1, w2, s2, d2);
    k_prep_w<<<2048, 256, 0, stream>>>(w1, w2, wA1, wA2);
    k_prep_x<<<dim3(32, 8), 256, 0, stream>>>(x, s1, xmh);
    k_conv1s<<<dim3(9, 4, 32), 256, 0, stream>>>(xmh, wA1, ctp);
    k_blur1<<<dim3(8, 64, 8), dim3(64, 4), 0, stream>>>(ctp, d1, noise1, nw1, bias1, s2, in1h);
    k_conv2<<<dim3(32, 4, 8), 256, 0, stream>>>(in1h, wA2, d2, noise2, nw2, bias2, s3, in2);
    k_rgb<<<8192, 256, 0, stream>>>(in2, w3, bias3, skiprgb, out);
}